// Round 8
// baseline (102.360 us; speedup 1.0000x reference)
//
#include <hip/hip_runtime.h>
#include <hip/hip_fp16.h>

// Problem constants: L=4, DIM=17, S=4, B=4, H=256, W=256, BINSIZE=16
#define HH   256
#define WW   256
#define HWPX (HH * WW)           // 65536
#define DD   17
#define D4   (17 * 17 * 17 * 17) // 83521
#define NL   4
#define SS   16                  // S*S
#define LUT_FLOATS  (NL * D4 * SS)            // 5,345,344 floats
#define LUT_BYTES_H ((size_t)LUT_FLOATS * 2)  // ~10.7 MB (fp16 transposed copy)

// clang ext_vector types: required by __builtin_nontemporal_load/store
// (HIP_vector_type float4/float2 are rejected).
typedef float v4f __attribute__((ext_vector_type(4)));
typedef float v2f __attribute__((ext_vector_type(2)));

// ---------------------------------------------------------------------------
// Kernel 1: transpose + fp16-convert LUT (L, D4, 16) f32 -> (D4, L, 16) f16.
// One vertex's four l-rows become exactly ONE 128B cache line.
// Source read is nontemporal (pure stream, zero reuse); dst write stays
// cacheable so the main kernel finds lutT warm in L2/L3.
// ---------------------------------------------------------------------------
__global__ __launch_bounds__(256) void lut_transpose_h_kernel(
    const v4f* __restrict__ src,      // (L, D4, 4) float4-chunks
    ushort* __restrict__ dst)         // (D4, L, 16) halfs as ushort
{
    int t = blockIdx.x * blockDim.x + threadIdx.x;  // 4-half chunk index in dst
    if (t >= D4 * NL * 4) return;
    int c4 = t & 3;
    int l  = (t >> 2) & 3;
    int v  = t >> 4;
    v4f r = __builtin_nontemporal_load(src + (size_t)l * (D4 * 4) + (size_t)v * 4 + c4);
    ushort4 h;
    h.x = __half_as_ushort(__float2half_rn(r.x));
    h.y = __half_as_ushort(__float2half_rn(r.y));
    h.z = __half_as_ushort(__float2half_rn(r.z));
    h.w = __half_as_ushort(__float2half_rn(r.w));
    *((ushort4*)(dst + (size_t)t * 4)) = h;   // coalesced 8B stores (cacheable)
}

// ---------------------------------------------------------------------------
// Kernel 2: main interpolation. 8 lanes per pixel; lane j handles channel
// pair (2j, 2j+1). Per (k,l): one 4B gather (2 halfs). Lanes j=0..7 cover
// each 32B l-row contiguously; one vertex = one fully-used 128B line.
// Output stores are NONTEMPORAL: the 67 MB write stream must not evict
// LUT lines from L2 (10.7 MB LUT vs 4 MB/XCD L2 -> every eviction is an
// extra L3 round-trip).
// ---------------------------------------------------------------------------
__global__ __launch_bounds__(256) void lut4d_kernel_o(
    const ushort* __restrict__ lutT,   // (D4, L, 16) fp16
    const float* __restrict__ weight,  // (B, L, H, W)
    const float* __restrict__ x,       // (B, 1, H, W)
    float* __restrict__ out)           // (B, 1, H*4, W*4)
{
    int tid = blockIdx.x * blockDim.x + threadIdx.x;  // [0, 8*B*H*W)
    int j = tid & 7;          // channel pair index: channels 2j, 2j+1
    int p = tid >> 3;         // pixel id
    int b  = p >> 16;
    int hw = p & 65535;
    int h  = hw >> 8;
    int w  = hw & 255;

    const float* xb = x + b * HWPX;
    int h1 = (h + 1 < HH) ? (h + 1) : (HH - 2);   // reflect pad
    int w1 = (w + 1 < WW) ? (w + 1) : (WW - 2);

    float pix0 = xb[h  * WW + w ];
    float pix1 = xb[h  * WW + w1];
    float pix2 = xb[h1 * WW + w ];
    float pix3 = xb[h1 * WW + w1];

    const float inv = 1.0f / 16.0f;
    float t0 = pix0 * inv, t1 = pix1 * inv, t2 = pix2 * inv, t3 = pix3 * inv;
    float bf0 = floorf(t0), bf1 = floorf(t1), bf2 = floorf(t2), bf3 = floorf(t3);
    float f0 = t0 - bf0, f1 = t1 - bf1, f2 = t2 - bf2, f3 = t3 - bf3;

    int b0 = min(max((int)bf0, 0), DD - 2);
    int b1 = min(max((int)bf1, 0), DD - 2);
    int b2 = min(max((int)bf2, 0), DD - 2);
    int b3 = min(max((int)bf3, 0), DD - 2);

    // Stable descending sort of (frac, stride); strides strictly decrease
    // with original index so tie-break by larger stride == stable argsort.
    float s0f = f0, s1f = f1, s2f = f2, s3f = f3;
    int   s0s = 4913, s1s = 289, s2s = 17, s3s = 1;

#define CSWAP(fa, sa, fb, sb)                                          \
    do {                                                               \
        bool sw = (fb > fa) || ((fb == fa) && (sb > sa));              \
        float tf = fa; int ts = sa;                                    \
        if (sw) { fa = fb; sa = sb; fb = tf; sb = ts; }                \
    } while (0)

    CSWAP(s0f, s0s, s1f, s1s);
    CSWAP(s2f, s2s, s3f, s3s);
    CSWAP(s0f, s0s, s2f, s2s);
    CSWAP(s1f, s1s, s3f, s3s);
    CSWAP(s1f, s1s, s2f, s2s);
#undef CSWAP

    float wts[5];
    wts[0] = 1.0f - s0f;
    wts[1] = s0f - s1f;
    wts[2] = s1f - s2f;
    wts[3] = s2f - s3f;
    wts[4] = s3f;

    int flats[5];
    flats[0] = ((b0 * DD + b1) * DD + b2) * DD + b3;
    flats[1] = flats[0] + s0s;
    flats[2] = flats[1] + s1s;
    flats[3] = flats[2] + s2s;
    flats[4] = flats[3] + s3s;

    const float* wb = weight + b * (NL * HWPX) + hw;
    float wl[NL];
#pragma unroll
    for (int l = 0; l < NL; ++l) wl[l] = wb[l * HWPX];

    // Issue all 20 independent 4B gathers, then convert + FMA.
    unsigned int r[5][NL];
#pragma unroll
    for (int k = 0; k < 5; ++k) {
        const ushort* vbase = lutT + (size_t)flats[k] * (NL * SS);
#pragma unroll
        for (int l = 0; l < NL; ++l) {
            r[k][l] = *((const unsigned int*)(vbase + l * SS + j * 2));
        }
    }

    float a0 = 0.f, a1 = 0.f;
#pragma unroll
    for (int k = 0; k < 5; ++k) {
#pragma unroll
        for (int l = 0; l < NL; ++l) {
            float c = wl[l] * wts[k];
            __half2 h01 = *reinterpret_cast<const __half2*>(&r[k][l]);
            float2 f01 = __half22float2(h01);
            a0 = fmaf(c, f01.x, a0);
            a1 = fmaf(c, f01.y, a1);
        }
    }

    // channels (2j, 2j+1) -> out[b, 0, h*4 + (j>>1), w*4 + (j&1)*2 .. +1]
    float* ob = out + (size_t)b * (HH * 4) * (WW * 4)
                    + (size_t)(h * 4 + (j >> 1)) * (WW * 4)
                    + (w * 4) + ((j & 1) * 2);
    v2f res; res.x = a0; res.y = a1;
    __builtin_nontemporal_store(res, (v2f*)ob);
}

// ---------------------------------------------------------------------------
// Fallback (no workspace): original layout, fp32.
// ---------------------------------------------------------------------------
__global__ __launch_bounds__(256) void lut4d_kernel_fallback(
    const float* __restrict__ lut,
    const float* __restrict__ weight,
    const float* __restrict__ x,
    float* __restrict__ out)
{
    int p = blockIdx.x * blockDim.x + threadIdx.x;
    int b  = p >> 16;
    int hw = p & 65535;
    int h  = hw >> 8;
    int w  = hw & 255;

    const float* xb = x + b * HWPX;
    int h1 = (h + 1 < HH) ? (h + 1) : (HH - 2);
    int w1 = (w + 1 < WW) ? (w + 1) : (WW - 2);

    float pix0 = xb[h  * WW + w ];
    float pix1 = xb[h  * WW + w1];
    float pix2 = xb[h1 * WW + w ];
    float pix3 = xb[h1 * WW + w1];

    const float inv = 1.0f / 16.0f;
    float t0 = pix0 * inv, t1 = pix1 * inv, t2 = pix2 * inv, t3 = pix3 * inv;
    float bf0 = floorf(t0), bf1 = floorf(t1), bf2 = floorf(t2), bf3 = floorf(t3);
    float f0 = t0 - bf0, f1 = t1 - bf1, f2 = t2 - bf2, f3 = t3 - bf3;

    int b0 = min(max((int)bf0, 0), DD - 2);
    int b1 = min(max((int)bf1, 0), DD - 2);
    int b2 = min(max((int)bf2, 0), DD - 2);
    int b3 = min(max((int)bf3, 0), DD - 2);

    float s0f = f0, s1f = f1, s2f = f2, s3f = f3;
    int   s0s = 4913, s1s = 289, s2s = 17, s3s = 1;

#define CSWAP(fa, sa, fb, sb)                                          \
    do {                                                               \
        bool sw = (fb > fa) || ((fb == fa) && (sb > sa));              \
        float tf = fa; int ts = sa;                                    \
        if (sw) { fa = fb; sa = sb; fb = tf; sb = ts; }                \
    } while (0)

    CSWAP(s0f, s0s, s1f, s1s);
    CSWAP(s2f, s2s, s3f, s3s);
    CSWAP(s0f, s0s, s2f, s2s);
    CSWAP(s1f, s1s, s3f, s3s);
    CSWAP(s1f, s1s, s2f, s2s);
#undef CSWAP

    float wts[5] = { 1.0f - s0f, s0f - s1f, s1f - s2f, s2f - s3f, s3f };
    int flats[5];
    flats[0] = ((b0 * DD + b1) * DD + b2) * DD + b3;
    flats[1] = flats[0] + s0s;
    flats[2] = flats[1] + s1s;
    flats[3] = flats[2] + s2s;
    flats[4] = flats[3] + s3s;

    float acc[SS];
#pragma unroll
    for (int i = 0; i < SS; ++i) acc[i] = 0.0f;

    const float* wb = weight + b * (NL * HWPX) + hw;

#pragma unroll
    for (int l = 0; l < NL; ++l) {
        float wlv = wb[l * HWPX];
        const float* lbase = lut + (size_t)l * D4 * SS;
#pragma unroll
        for (int k = 0; k < 5; ++k) {
            float c = wlv * wts[k];
            const float4* row = (const float4*)(lbase + (size_t)flats[k] * SS);
#pragma unroll
            for (int q = 0; q < 4; ++q) {
                float4 rr = row[q];
                acc[q * 4 + 0] = fmaf(c, rr.x, acc[q * 4 + 0]);
                acc[q * 4 + 1] = fmaf(c, rr.y, acc[q * 4 + 1]);
                acc[q * 4 + 2] = fmaf(c, rr.z, acc[q * 4 + 2]);
                acc[q * 4 + 3] = fmaf(c, rr.w, acc[q * 4 + 3]);
            }
        }
    }

    float* ob = out + (size_t)b * (HH * 4) * (WW * 4) + (size_t)(h * 4) * (WW * 4) + (w * 4);
#pragma unroll
    for (int i = 0; i < 4; ++i) {
        *((float4*)(ob + (size_t)i * (WW * 4))) =
            make_float4(acc[i * 4 + 0], acc[i * 4 + 1], acc[i * 4 + 2], acc[i * 4 + 3]);
    }
}

extern "C" void kernel_launch(void* const* d_in, const int* in_sizes, int n_in,
                              void* d_out, int out_size, void* d_ws, size_t ws_size,
                              hipStream_t stream) {
    const float* lut    = (const float*)d_in[0];
    // d_in[1] = tri_index (unused by the reference computation)
    const float* weight = (const float*)d_in[2];
    const float* x      = (const float*)d_in[3];
    float* out          = (float*)d_out;

    dim3 block(256);

    if (ws_size >= LUT_BYTES_H) {
        ushort* lutT = (ushort*)d_ws;
        int n_chunks = D4 * NL * 4;                   // 1,336,336 4-half chunks
        dim3 grid_t((n_chunks + 255) / 256);
        hipLaunchKernelGGL(lut_transpose_h_kernel, grid_t, block, 0, stream,
                           (const v4f*)lut, lutT);
        dim3 grid_main(8192);   // 8 * 262144 threads / 256
        hipLaunchKernelGGL(lut4d_kernel_o, grid_main, block, 0, stream,
                           lutT, weight, x, out);
    } else {
        dim3 grid_main(1024);
        hipLaunchKernelGGL(lut4d_kernel_fallback, grid_main, block, 0, stream,
                           lut, weight, x, out);
    }
}

// Round 9
// 99.602 us; speedup vs baseline: 1.0277x; 1.0277x over previous
//
#include <hip/hip_runtime.h>
#include <hip/hip_fp16.h>

// Problem constants: L=4, DIM=17, S=4, B=4, H=256, W=256, BINSIZE=16
#define HH   256
#define WW   256
#define HWPX (HH * WW)           // 65536
#define DD   17
#define D4   (17 * 17 * 17 * 17) // 83521
#define NL   4
#define SS   16                  // S*S
#define LUT_FLOATS  (NL * D4 * SS)            // 5,345,344 floats
#define LUT_BYTES_H ((size_t)LUT_FLOATS * 2)  // ~10.7 MB (fp16 transposed copy)

// ---------------------------------------------------------------------------
// Structural-floor accounting (measured R1-R8):
//   dur_us ~= 72us harness restore/poison (fixed, fillBufferAligned rows)
//           +  ~6us transpose (32 MB stream at ~5.8 TB/s, at stream ceiling)
//           + ~21us main (168 MB random 128B-line gathers, every byte used;
//                         fp16 is the accuracy floor - fp8 absmax ~1.2 > 0.109)
// Experiments that did NOT move the main kernel: 2x MLP (R5), minimal
// line-transactions via 16-lane+shfl (R6), nontemporal out-stream (R8).
// ---------------------------------------------------------------------------

// ---------------------------------------------------------------------------
// Kernel 1: transpose + fp16-convert LUT (L, D4, 16) f32 -> (D4, L, 16) f16.
// One vertex's four l-rows become exactly ONE 128B cache line.
// ---------------------------------------------------------------------------
__global__ __launch_bounds__(256) void lut_transpose_h_kernel(
    const float4* __restrict__ src,   // (L, D4, 4) float4
    ushort* __restrict__ dst)         // (D4, L, 16) halfs as ushort
{
    int t = blockIdx.x * blockDim.x + threadIdx.x;  // 4-half chunk index in dst
    if (t >= D4 * NL * 4) return;
    int c4 = t & 3;
    int l  = (t >> 2) & 3;
    int v  = t >> 4;
    float4 r = src[(size_t)l * (D4 * 4) + (size_t)v * 4 + c4];
    ushort4 h;
    h.x = __half_as_ushort(__float2half_rn(r.x));
    h.y = __half_as_ushort(__float2half_rn(r.y));
    h.z = __half_as_ushort(__float2half_rn(r.z));
    h.w = __half_as_ushort(__float2half_rn(r.w));
    *((ushort4*)(dst + (size_t)t * 4)) = h;   // coalesced 8B stores
}

// ---------------------------------------------------------------------------
// Kernel 2: main interpolation. 8 lanes per pixel; lane j handles channel
// pair (2j, 2j+1). Per (k,l): one 4B gather (2 halfs). Lanes j=0..7 cover
// each 32B l-row contiguously; one vertex = one fully-used 128B line.
// ---------------------------------------------------------------------------
__global__ __launch_bounds__(256) void lut4d_kernel_o(
    const ushort* __restrict__ lutT,   // (D4, L, 16) fp16
    const float* __restrict__ weight,  // (B, L, H, W)
    const float* __restrict__ x,       // (B, 1, H, W)
    float* __restrict__ out)           // (B, 1, H*4, W*4)
{
    int tid = blockIdx.x * blockDim.x + threadIdx.x;  // [0, 8*B*H*W)
    int j = tid & 7;          // channel pair index: channels 2j, 2j+1
    int p = tid >> 3;         // pixel id
    int b  = p >> 16;
    int hw = p & 65535;
    int h  = hw >> 8;
    int w  = hw & 255;

    const float* xb = x + b * HWPX;
    int h1 = (h + 1 < HH) ? (h + 1) : (HH - 2);   // reflect pad
    int w1 = (w + 1 < WW) ? (w + 1) : (WW - 2);

    float pix0 = xb[h  * WW + w ];
    float pix1 = xb[h  * WW + w1];
    float pix2 = xb[h1 * WW + w ];
    float pix3 = xb[h1 * WW + w1];

    const float inv = 1.0f / 16.0f;
    float t0 = pix0 * inv, t1 = pix1 * inv, t2 = pix2 * inv, t3 = pix3 * inv;
    float bf0 = floorf(t0), bf1 = floorf(t1), bf2 = floorf(t2), bf3 = floorf(t3);
    float f0 = t0 - bf0, f1 = t1 - bf1, f2 = t2 - bf2, f3 = t3 - bf3;

    int b0 = min(max((int)bf0, 0), DD - 2);
    int b1 = min(max((int)bf1, 0), DD - 2);
    int b2 = min(max((int)bf2, 0), DD - 2);
    int b3 = min(max((int)bf3, 0), DD - 2);

    // Stable descending sort of (frac, stride); strides strictly decrease
    // with original index so tie-break by larger stride == stable argsort.
    float s0f = f0, s1f = f1, s2f = f2, s3f = f3;
    int   s0s = 4913, s1s = 289, s2s = 17, s3s = 1;

#define CSWAP(fa, sa, fb, sb)                                          \
    do {                                                               \
        bool sw = (fb > fa) || ((fb == fa) && (sb > sa));              \
        float tf = fa; int ts = sa;                                    \
        if (sw) { fa = fb; sa = sb; fb = tf; sb = ts; }                \
    } while (0)

    CSWAP(s0f, s0s, s1f, s1s);
    CSWAP(s2f, s2s, s3f, s3s);
    CSWAP(s0f, s0s, s2f, s2s);
    CSWAP(s1f, s1s, s3f, s3s);
    CSWAP(s1f, s1s, s2f, s2s);
#undef CSWAP

    float wts[5];
    wts[0] = 1.0f - s0f;
    wts[1] = s0f - s1f;
    wts[2] = s1f - s2f;
    wts[3] = s2f - s3f;
    wts[4] = s3f;

    int flats[5];
    flats[0] = ((b0 * DD + b1) * DD + b2) * DD + b3;
    flats[1] = flats[0] + s0s;
    flats[2] = flats[1] + s1s;
    flats[3] = flats[2] + s2s;
    flats[4] = flats[3] + s3s;

    const float* wb = weight + b * (NL * HWPX) + hw;
    float wl[NL];
#pragma unroll
    for (int l = 0; l < NL; ++l) wl[l] = wb[l * HWPX];

    // Issue all 20 independent 4B gathers, then convert + FMA.
    unsigned int r[5][NL];
#pragma unroll
    for (int k = 0; k < 5; ++k) {
        const ushort* vbase = lutT + (size_t)flats[k] * (NL * SS);
#pragma unroll
        for (int l = 0; l < NL; ++l) {
            r[k][l] = *((const unsigned int*)(vbase + l * SS + j * 2));
        }
    }

    float a0 = 0.f, a1 = 0.f;
#pragma unroll
    for (int k = 0; k < 5; ++k) {
#pragma unroll
        for (int l = 0; l < NL; ++l) {
            float c = wl[l] * wts[k];
            __half2 h01 = *reinterpret_cast<const __half2*>(&r[k][l]);
            float2 f01 = __half22float2(h01);
            a0 = fmaf(c, f01.x, a0);
            a1 = fmaf(c, f01.y, a1);
        }
    }

    // channels (2j, 2j+1) -> out[b, 0, h*4 + (j>>1), w*4 + (j&1)*2 .. +1]
    float* ob = out + (size_t)b * (HH * 4) * (WW * 4)
                    + (size_t)(h * 4 + (j >> 1)) * (WW * 4)
                    + (w * 4) + ((j & 1) * 2);
    *((float2*)ob) = make_float2(a0, a1);
}

// ---------------------------------------------------------------------------
// Fallback (no workspace): original layout, fp32.
// ---------------------------------------------------------------------------
__global__ __launch_bounds__(256) void lut4d_kernel_fallback(
    const float* __restrict__ lut,
    const float* __restrict__ weight,
    const float* __restrict__ x,
    float* __restrict__ out)
{
    int p = blockIdx.x * blockDim.x + threadIdx.x;
    int b  = p >> 16;
    int hw = p & 65535;
    int h  = hw >> 8;
    int w  = hw & 255;

    const float* xb = x + b * HWPX;
    int h1 = (h + 1 < HH) ? (h + 1) : (HH - 2);
    int w1 = (w + 1 < WW) ? (w + 1) : (WW - 2);

    float pix0 = xb[h  * WW + w ];
    float pix1 = xb[h  * WW + w1];
    float pix2 = xb[h1 * WW + w ];
    float pix3 = xb[h1 * WW + w1];

    const float inv = 1.0f / 16.0f;
    float t0 = pix0 * inv, t1 = pix1 * inv, t2 = pix2 * inv, t3 = pix3 * inv;
    float bf0 = floorf(t0), bf1 = floorf(t1), bf2 = floorf(t2), bf3 = floorf(t3);
    float f0 = t0 - bf0, f1 = t1 - bf1, f2 = t2 - bf2, f3 = t3 - bf3;

    int b0 = min(max((int)bf0, 0), DD - 2);
    int b1 = min(max((int)bf1, 0), DD - 2);
    int b2 = min(max((int)bf2, 0), DD - 2);
    int b3 = min(max((int)bf3, 0), DD - 2);

    float s0f = f0, s1f = f1, s2f = f2, s3f = f3;
    int   s0s = 4913, s1s = 289, s2s = 17, s3s = 1;

#define CSWAP(fa, sa, fb, sb)                                          \
    do {                                                               \
        bool sw = (fb > fa) || ((fb == fa) && (sb > sa));              \
        float tf = fa; int ts = sa;                                    \
        if (sw) { fa = fb; sa = sb; fb = tf; sb = ts; }                \
    } while (0)

    CSWAP(s0f, s0s, s1f, s1s);
    CSWAP(s2f, s2s, s3f, s3s);
    CSWAP(s0f, s0s, s2f, s2s);
    CSWAP(s1f, s1s, s3f, s3s);
    CSWAP(s1f, s1s, s2f, s2s);
#undef CSWAP

    float wts[5] = { 1.0f - s0f, s0f - s1f, s1f - s2f, s2f - s3f, s3f };
    int flats[5];
    flats[0] = ((b0 * DD + b1) * DD + b2) * DD + b3;
    flats[1] = flats[0] + s0s;
    flats[2] = flats[1] + s1s;
    flats[3] = flats[2] + s2s;
    flats[4] = flats[3] + s3s;

    float acc[SS];
#pragma unroll
    for (int i = 0; i < SS; ++i) acc[i] = 0.0f;

    const float* wb = weight + b * (NL * HWPX) + hw;

#pragma unroll
    for (int l = 0; l < NL; ++l) {
        float wlv = wb[l * HWPX];
        const float* lbase = lut + (size_t)l * D4 * SS;
#pragma unroll
        for (int k = 0; k < 5; ++k) {
            float c = wlv * wts[k];
            const float4* row = (const float4*)(lbase + (size_t)flats[k] * SS);
#pragma unroll
            for (int q = 0; q < 4; ++q) {
                float4 rr = row[q];
                acc[q * 4 + 0] = fmaf(c, rr.x, acc[q * 4 + 0]);
                acc[q * 4 + 1] = fmaf(c, rr.y, acc[q * 4 + 1]);
                acc[q * 4 + 2] = fmaf(c, rr.z, acc[q * 4 + 2]);
                acc[q * 4 + 3] = fmaf(c, rr.w, acc[q * 4 + 3]);
            }
        }
    }

    float* ob = out + (size_t)b * (HH * 4) * (WW * 4) + (size_t)(h * 4) * (WW * 4) + (w * 4);
#pragma unroll
    for (int i = 0; i < 4; ++i) {
        *((float4*)(ob + (size_t)i * (WW * 4))) =
            make_float4(acc[i * 4 + 0], acc[i * 4 + 1], acc[i * 4 + 2], acc[i * 4 + 3]);
    }
}

extern "C" void kernel_launch(void* const* d_in, const int* in_sizes, int n_in,
                              void* d_out, int out_size, void* d_ws, size_t ws_size,
                              hipStream_t stream) {
    const float* lut    = (const float*)d_in[0];
    // d_in[1] = tri_index (unused by the reference computation)
    const float* weight = (const float*)d_in[2];
    const float* x      = (const float*)d_in[3];
    float* out          = (float*)d_out;

    dim3 block(256);

    if (ws_size >= LUT_BYTES_H) {
        ushort* lutT = (ushort*)d_ws;
        int n_chunks = D4 * NL * 4;                   // 1,336,336 4-half chunks
        dim3 grid_t((n_chunks + 255) / 256);
        hipLaunchKernelGGL(lut_transpose_h_kernel, grid_t, block, 0, stream,
                           (const float4*)lut, lutT);
        dim3 grid_main(8192);   // 8 * 262144 threads / 256
        hipLaunchKernelGGL(lut4d_kernel_o, grid_main, block, 0, stream,
                           lutT, weight, x, out);
    } else {
        dim3 grid_main(1024);
        hipLaunchKernelGGL(lut4d_kernel_fallback, grid_main, block, 0, stream,
                           lut, weight, x, out);
    }
}